// Round 10
// baseline (122.149 us; speedup 1.0000x reference)
//
#include <hip/hip_runtime.h>
#include <hip/hip_bf16.h>

#define NB 4096
#define ND 512

typedef int i32x4 __attribute__((ext_vector_type(4)));
typedef int i32x8 __attribute__((ext_vector_type(8)));
typedef float f32x4 __attribute__((ext_vector_type(4)));

// ---- f32 -> fp8 e4m3fn (OCP), RNE, |x| <= 1 ----
__device__ __forceinline__ unsigned int f2e4m3(float x) {
    float a = fabsf(x);
    unsigned s = (__float_as_uint(x) >> 24) & 0x80u;
    if (a < 0.015625f) {                       // denorm/zero: step 2^-9
        int q = __float2int_rn(a * 512.0f);    // 0..8 (8 -> 0x08 == 2^-6)
        return s | (unsigned)q;
    }
    unsigned u = __float_as_uint(a);
    u += 0x7FFFFu + ((u >> 20) & 1u);          // RNE to 3-bit mantissa
    unsigned e8 = (u >> 23) - 120u;            // 1..7 for a in [2^-6, 1]
    unsigned m = (u >> 20) & 7u;
    return s | (e8 << 3) | m;
}

// ---------------- normalize + cast to fp8 (wave per row) + zero-init sums ----------------
__global__ __launch_bounds__(256) void nrm_kernel(
    const float* __restrict__ z0, const float* __restrict__ z1,
    const float* __restrict__ z2, unsigned char* __restrict__ nrm8,
    float* __restrict__ rowsum, float* __restrict__ colsum)
{
    const int w = threadIdx.x >> 6, lane = threadIdx.x & 63;
    const int row = blockIdx.x * 4 + w;
    const int p = blockIdx.y;
    if (lane == 0) {
        rowsum[p * NB + row] = 0.f;
        colsum[p * NB + row] = 0.f;
    }
    const float* z = (p == 0) ? z0 : (p == 1) ? z1 : z2;
    const float4* zr = (const float4*)(z + (size_t)row * ND);
    const float4 a = zr[lane * 2], b = zr[lane * 2 + 1];
    float ss = a.x * a.x + a.y * a.y + a.z * a.z + a.w * a.w
             + b.x * b.x + b.y * b.y + b.z * b.z + b.w * b.w;
    #pragma unroll
    for (int m = 32; m >= 1; m >>= 1) ss += __shfl_xor(ss, m);
    const float inv = 1.0f / fmaxf(sqrtf(ss), 1e-8f);
    uint2 o;
    o.x = f2e4m3(a.x * inv) | (f2e4m3(a.y * inv) << 8)
        | (f2e4m3(a.z * inv) << 16) | (f2e4m3(a.w * inv) << 24);
    o.y = f2e4m3(b.x * inv) | (f2e4m3(b.y * inv) << 8)
        | (f2e4m3(b.z * inv) << 16) | (f2e4m3(b.w * inv) << 24);
    *(uint2*)(nrm8 + ((size_t)p * NB + row) * ND + lane * 8) = o;
}

// ---------------- fused pair GEMM, MX-fp8, LDS-FREE ----------------
// One wave per 64x64 output tile. Fragments loaded straight from L2 into
// registers (working set is L2/L3-resident; LDS staging was pure overhead).
// 4 K-steps of 16x16x128 MFMA, register double-buffered, zero barriers,
// per-wave compiler-counted vmcnt. 12288 one-wave blocks, XCD-chunked.
__global__ __launch_bounds__(64, 2) void pair_gemm_kernel(
    const unsigned char* __restrict__ nrm8,
    float* __restrict__ rowsum, float* __restrict__ colsum,
    float* __restrict__ diag)
{
    // 12288 blocks = 8 xcd x (3 pair x 8 by x 64 bx). Per pair per XCD:
    // A slice 8*64 rows (256 KB) + full B panel (2 MB) < 4 MB L2. Bijective.
    const int bid = blockIdx.x;
    const int xcd = bid & 7;
    const int rank = bid >> 3;            // 0..1535
    const int p = rank >> 9;              // 0..2
    const int r = rank & 511;
    const int by = xcd * 8 + (r >> 6);    // 0..63
    const int bx = r & 63;                // 0..63
    const int ia = (p == 2) ? 1 : 0;
    const int ib = (p == 0) ? 1 : 2;

    const char* Ag = (const char*)nrm8 + ((size_t)ia * NB + (size_t)by * 64) * ND;
    const char* Bg = (const char*)nrm8 + ((size_t)ib * NB + (size_t)bx * 64) * ND;

    const int lane = threadIdx.x;
    const int lr = lane & 15, lg = lane >> 4;

    // Per-lane fragment base pointers: frag row = m*16 + lr, k-bytes 32*lg..+32
    // (identical logical k-map for A and B as rounds 6-9 -> any HW-internal
    // k permutation cancels in the A.B^T contraction). K-step t adds t*128.
    const char* pa[4];
    const char* pb[4];
    #pragma unroll
    for (int m = 0; m < 4; ++m) {
        pa[m] = Ag + (m * 16 + lr) * ND + lg * 32;
        pb[m] = Bg + (m * 16 + lr) * ND + lg * 32;
    }

    f32x4 acc[4][4] = {};

    // load step t into half-registers (use site is the MFMA cluster, so the
    // compiler's auto waitcnt lands there -> loads stay in flight meanwhile)
    #define LOADSTEP(AL, AH, BL, BH, t) do {                                        \
        _Pragma("unroll")                                                           \
        for (int m = 0; m < 4; ++m) {                                               \
            AL[m] = *(const i32x4*)(pa[m] + (t) * 128);                             \
            AH[m] = *(const i32x4*)(pa[m] + (t) * 128 + 16);                        \
        }                                                                           \
        _Pragma("unroll")                                                           \
        for (int n = 0; n < 4; ++n) {                                               \
            BL[n] = *(const i32x4*)(pb[n] + (t) * 128);                             \
            BH[n] = *(const i32x4*)(pb[n] + (t) * 128 + 16);                        \
        }                                                                           \
    } while (0)

    #define SC 0x7F7F7F7F
    #define MFMASTEP(AL, AH, BL, BH) do {                                           \
        i32x8 af_[4], bf_[4];                                                       \
        _Pragma("unroll")                                                           \
        for (int m = 0; m < 4; ++m)                                                 \
            af_[m] = __builtin_shufflevector(AL[m], AH[m], 0, 1, 2, 3, 4, 5, 6, 7); \
        _Pragma("unroll")                                                           \
        for (int n = 0; n < 4; ++n)                                                 \
            bf_[n] = __builtin_shufflevector(BL[n], BH[n], 0, 1, 2, 3, 4, 5, 6, 7); \
        __builtin_amdgcn_s_setprio(1);                                              \
        _Pragma("unroll")                                                           \
        for (int m = 0; m < 4; ++m)                                                 \
            _Pragma("unroll")                                                       \
            for (int n = 0; n < 4; ++n)                                             \
                acc[m][n] = __builtin_amdgcn_mfma_scale_f32_16x16x128_f8f6f4(       \
                    af_[m], bf_[n], acc[m][n], 0, 0, 0, SC, 0, SC);                 \
        __builtin_amdgcn_s_setprio(0);                                              \
    } while (0)

    // 2-deep register pipeline over the 4 K-steps, no sync anywhere
    i32x4 aL0[4], aH0[4], bL0[4], bH0[4];
    i32x4 aL1[4], aH1[4], bL1[4], bH1[4];
    LOADSTEP(aL0, aH0, bL0, bH0, 0);
    LOADSTEP(aL1, aH1, bL1, bH1, 1);
    MFMASTEP(aL0, aH0, bL0, bH0);          // step 0
    LOADSTEP(aL0, aH0, bL0, bH0, 2);
    MFMASTEP(aL1, aH1, bL1, bH1);          // step 1
    LOADSTEP(aL1, aH1, bL1, bH1, 3);
    MFMASTEP(aL0, aH0, bL0, bH0);          // step 2
    MFMASTEP(aL1, aH1, bL1, bH1);          // step 3

    #undef LOADSTEP
    #undef MFMASTEP

    // ---- diag (pre-exp): C frag row = lg*4+j (within 16), col = lr ----
    if (bx == by) {
        #pragma unroll
        for (int m = 0; m < 4; ++m)
            #pragma unroll
            for (int j = 0; j < 4; ++j)
                if (lr == lg * 4 + j)
                    diag[p * NB + by * 64 + m * 16 + lr] = acc[m][m][j];
    }

    // ---- epilogue: e = exp2(sim*10*log2e - 10*log2e), row/col partials ----
    constexpr float C10 = 14.42695040888963f;
    float rs[4][4];
    float cs[4] = {0.f, 0.f, 0.f, 0.f};
    #pragma unroll
    for (int m = 0; m < 4; ++m)
        #pragma unroll
        for (int j = 0; j < 4; ++j) rs[m][j] = 0.f;

    #pragma unroll
    for (int m = 0; m < 4; ++m)
        #pragma unroll
        for (int n = 0; n < 4; ++n)
            #pragma unroll
            for (int j = 0; j < 4; ++j) {
                float e = exp2f(fmaf(acc[m][n][j], C10, -C10));
                rs[m][j] += e;
                cs[n] += e;
            }

    #pragma unroll
    for (int m = 0; m < 4; ++m)
        #pragma unroll
        for (int j = 0; j < 4; ++j) {
            float v = rs[m][j];
            v += __shfl_xor(v, 1);
            v += __shfl_xor(v, 2);
            v += __shfl_xor(v, 4);
            v += __shfl_xor(v, 8);
            rs[m][j] = v;
        }
    #pragma unroll
    for (int n = 0; n < 4; ++n) {
        float v = cs[n];
        v += __shfl_xor(v, 16);
        v += __shfl_xor(v, 32);
        cs[n] = v;
    }

    float* rowp = rowsum + p * NB + by * 64;
    float* colp = colsum + p * NB + bx * 64;
    if (lr == 0) {
        #pragma unroll
        for (int m = 0; m < 4; ++m)
            #pragma unroll
            for (int j = 0; j < 4; ++j)
                atomicAdd(&rowp[m * 16 + lg * 4 + j], rs[m][j]);
    }
    if (lg == 0) {
        #pragma unroll
        for (int n = 0; n < 4; ++n)
            atomicAdd(&colp[n * 16 + lr], cs[n]);
    }
}

// ---------------- final reduce ----------------
__global__ __launch_bounds__(1024) void finalize_kernel(
    const float* __restrict__ rowsum, const float* __restrict__ colsum,
    const float* __restrict__ diag, float* __restrict__ out)
{
    float s = 0.f;
    for (int i = threadIdx.x; i < 3 * NB; i += 1024) {
        s += 0.5f * (logf(rowsum[i]) + logf(colsum[i])) + 10.0f - 10.0f * diag[i];
    }
    #pragma unroll
    for (int m = 32; m >= 1; m >>= 1) s += __shfl_xor(s, m);
    __shared__ float sw[16];
    if ((threadIdx.x & 63) == 0) sw[threadIdx.x >> 6] = s;
    __syncthreads();
    if (threadIdx.x == 0) {
        float t = 0.f;
        #pragma unroll
        for (int i = 0; i < 16; ++i) t += sw[i];
        out[0] = t * (1.0f / (3.0f * NB));
    }
}

extern "C" void kernel_launch(void* const* d_in, const int* in_sizes, int n_in,
                              void* d_out, int out_size, void* d_ws, size_t ws_size,
                              hipStream_t stream) {
    const float* z0 = (const float*)d_in[0];
    const float* z1 = (const float*)d_in[1];
    const float* z2 = (const float*)d_in[2];
    float* out = (float*)d_out;

    char* ws = (char*)d_ws;
    unsigned char* nrm8 = (unsigned char*)ws;               // 3*4096*512 fp8 = 6.3 MB
    const size_t nrm_bytes = (size_t)3 * NB * ND;
    float* rowsum = (float*)(ws + nrm_bytes);               // 3*4096 f32
    float* colsum = rowsum + 3 * NB;                        // 3*4096 f32
    float* diag = colsum + 3 * NB;                          // 3*4096 f32 (fully overwritten)

    nrm_kernel<<<dim3(NB / 4, 3), 256, 0, stream>>>(z0, z1, z2, nrm8, rowsum, colsum);
    pair_gemm_kernel<<<12288, 64, 0, stream>>>(nrm8, rowsum, colsum, diag);
    finalize_kernel<<<1, 1024, 0, stream>>>(rowsum, colsum, diag, out);
}

// Round 11
// 65.965 us; speedup vs baseline: 1.8517x; 1.8517x over previous
//
#include <hip/hip_runtime.h>
#include <hip/hip_bf16.h>

#define NB 4096
#define ND 512

typedef int i32x4 __attribute__((ext_vector_type(4)));
typedef int i32x8 __attribute__((ext_vector_type(8)));
typedef float f32x4 __attribute__((ext_vector_type(4)));

#define AS1 __attribute__((address_space(1)))
#define AS3 __attribute__((address_space(3)))

// ---- f32 -> fp8 e4m3fn (OCP), RNE, |x| <= 1 ----
__device__ __forceinline__ unsigned int f2e4m3(float x) {
    float a = fabsf(x);
    unsigned s = (__float_as_uint(x) >> 24) & 0x80u;
    if (a < 0.015625f) {                       // denorm/zero: step 2^-9
        int q = __float2int_rn(a * 512.0f);    // 0..8 (8 -> 0x08 == 2^-6)
        return s | (unsigned)q;
    }
    unsigned u = __float_as_uint(a);
    u += 0x7FFFFu + ((u >> 20) & 1u);          // RNE to 3-bit mantissa
    unsigned e8 = (u >> 23) - 120u;            // 1..7 for a in [2^-6, 1]
    unsigned m = (u >> 20) & 7u;
    return s | (e8 << 3) | m;
}

// ---------------- normalize + cast to fp8 (wave per row) + zero-init sums ----------------
__global__ __launch_bounds__(256) void nrm_kernel(
    const float* __restrict__ z0, const float* __restrict__ z1,
    const float* __restrict__ z2, unsigned char* __restrict__ nrm8,
    float* __restrict__ rowsum, float* __restrict__ colsum)
{
    const int w = threadIdx.x >> 6, lane = threadIdx.x & 63;
    const int row = blockIdx.x * 4 + w;
    const int p = blockIdx.y;
    if (lane == 0) {
        rowsum[p * NB + row] = 0.f;
        colsum[p * NB + row] = 0.f;
    }
    const float* z = (p == 0) ? z0 : (p == 1) ? z1 : z2;
    const float4* zr = (const float4*)(z + (size_t)row * ND);
    const float4 a = zr[lane * 2], b = zr[lane * 2 + 1];
    float ss = a.x * a.x + a.y * a.y + a.z * a.z + a.w * a.w
             + b.x * b.x + b.y * b.y + b.z * b.z + b.w * b.w;
    #pragma unroll
    for (int m = 32; m >= 1; m >>= 1) ss += __shfl_xor(ss, m);
    const float inv = 1.0f / fmaxf(sqrtf(ss), 1e-8f);
    uint2 o;
    o.x = f2e4m3(a.x * inv) | (f2e4m3(a.y * inv) << 8)
        | (f2e4m3(a.z * inv) << 16) | (f2e4m3(a.w * inv) << 24);
    o.y = f2e4m3(b.x * inv) | (f2e4m3(b.y * inv) << 8)
        | (f2e4m3(b.z * inv) << 16) | (f2e4m3(b.w * inv) << 24);
    *(uint2*)(nrm8 + ((size_t)p * NB + row) * ND + lane * 8) = o;
}

// ---------------- fused pair GEMM, MX-fp8: 128 rows x 512 cols per block ----------------
// 16-stage pipeline (4 bx-tiles x 4 k-steps), r7's proven 64 KB double-buffer
// staging (2 blocks/CU). Per-bx epilogue overlaps the stage drain; rowsums
// held in registers across tiles. bxc = XCD -> B chunk L2-resident.
__global__ __launch_bounds__(256, 2) void pair_gemm_kernel(
    const unsigned char* __restrict__ nrm8,
    float* __restrict__ rowsum, float* __restrict__ colsum,
    float* __restrict__ diag)
{
    // 768 blocks: bxc = bid&7 (one 512-col B chunk per XCD); r = bid>>3:
    // p = r>>5 (0..2), by = r&31.
    const int bid = blockIdx.x;
    const int bxc = bid & 7;
    const int r = bid >> 3;
    const int p = r >> 5;
    const int by = r & 31;
    const int ia = (p == 2) ? 1 : 0;
    const int ib = (p == 0) ? 1 : 2;

    const char* Ag = (const char*)nrm8 + ((size_t)ia * NB + (size_t)by * 128) * ND;
    const char* Bg = (const char*)nrm8 + ((size_t)ib * NB + (size_t)bxc * 512) * ND;

    __shared__ char lds[65536];  // A bufs at 0,16384; B bufs at 32768,49152

    const int tid = threadIdx.x;
    const int lane = tid & 63;
    const int w = tid >> 6;
    const int wr = w >> 1, wc = w & 1;   // 2x2 wave grid; wave tile 64x64
    const int lr = lane & 15, lg = lane >> 4;

    // staging map (r6-8, proven): 16 KB subtile = 128 rows x 128 B; chunk
    // c = q*256+tid -> LDS linear c*16; source row rr = c>>3, phys slot
    // qp = c&7 holds logical qp^(rr&7) -> inverse-swizzled SOURCE (rule 21).
    int srcOff[4];
    #pragma unroll
    for (int q = 0; q < 4; ++q) {
        const int c = q * 256 + tid;
        const int rr = c >> 3;
        srcOff[q] = rr * ND + (((c & 7) ^ (rr & 7)) * 16);
    }

    // frag reads (r6-8, proven): logical slots {2lg, 2lg+1}, phys = ^(lr&7).
    const int s0 = ((2 * lg) ^ (lr & 7)) * 16;
    const int s1 = ((2 * lg + 1) ^ (lr & 7)) * 16;
    int arow[4], brow[4];
    #pragma unroll
    for (int m = 0; m < 4; ++m) {
        arow[m] = (wr * 64 + m * 16 + lr) * 128;
        brow[m] = (wc * 64 + m * 16 + lr) * 128;
    }

    f32x4 acc[4][4] = {};
    float rs[4][4];
    #pragma unroll
    for (int m = 0; m < 4; ++m)
        #pragma unroll
        for (int j = 0; j < 4; ++j) rs[m][j] = 0.f;

    #define STAGE(gsrc, dstbase) do {                                               \
        _Pragma("unroll")                                                           \
        for (int q = 0; q < 4; ++q)                                                 \
            __builtin_amdgcn_global_load_lds(                                       \
                (const AS1 void*)((gsrc) + srcOff[q]),                              \
                (AS3 void*)(lds + (dstbase) + q * 4096 + tid * 16), 16, 0, 0);      \
    } while (0)

    #define LDF(dst, base) do {                                                     \
        i32x4 lo_ = *(const i32x4*)((base) + s0);                                   \
        i32x4 hi_ = *(const i32x4*)((base) + s1);                                   \
        dst = __builtin_shufflevector(lo_, hi_, 0, 1, 2, 3, 4, 5, 6, 7);            \
    } while (0)

    #define SC 0x7F7F7F7F
    constexpr float C10 = 14.42695040888963f;

    // prologue: stage s=0 (A[0], B[0][0]) into buf 0
    STAGE(Ag, 0);
    STAGE(Bg, 32768);
    asm volatile("s_waitcnt vmcnt(0)" ::: "memory");
    __builtin_amdgcn_s_barrier();

    #pragma unroll 1
    for (int s = 0; s < 16; ++s) {
        const int bxl = s >> 2, k = s & 3;
        const int pb = s & 1;

        // issue stage s+1 into the other buffers (read last iter; all waves'
        // reads were consumed by their MFMAs before the last barrier -> safe)
        if (s < 15) {
            const int s1i = s + 1;
            const int po = s1i & 1;
            STAGE(Ag + (s1i & 3) * 128, po * 16384);
            STAGE(Bg + (size_t)(s1i >> 2) * 128 * ND + (s1i & 3) * 128,
                  32768 + po * 16384);
        }

        // fragments for stage s
        const char* ab = lds + pb * 16384;
        const char* bb = lds + 32768 + pb * 16384;
        i32x8 af[4], bf[4];
        #pragma unroll
        for (int m = 0; m < 4; ++m) LDF(af[m], ab + arow[m]);
        #pragma unroll
        for (int n = 0; n < 4; ++n) LDF(bf[n], bb + brow[n]);

        __builtin_amdgcn_s_setprio(1);
        #pragma unroll
        for (int m = 0; m < 4; ++m)
            #pragma unroll
            for (int n = 0; n < 4; ++n)
                acc[m][n] = __builtin_amdgcn_mfma_scale_f32_16x16x128_f8f6f4(
                    af[m], bf[n], acc[m][n], 0, 0, 0, SC, 0, SC);
        __builtin_amdgcn_s_setprio(0);

        // per-bx-tile epilogue (k==3): overlaps the stage-drain below
        if (k == 3) {
            const int bxg = bxc * 4 + bxl;
            if (by == bxg && wr == wc) {
                #pragma unroll
                for (int m = 0; m < 4; ++m)
                    #pragma unroll
                    for (int j = 0; j < 4; ++j)
                        if (lr == lg * 4 + j)
                            diag[p * NB + by * 128 + wr * 64 + m * 16 + lr] = acc[m][m][j];
            }
            float cs[4] = {0.f, 0.f, 0.f, 0.f};
            #pragma unroll
            for (int m = 0; m < 4; ++m)
                #pragma unroll
                for (int n = 0; n < 4; ++n)
                    #pragma unroll
                    for (int j = 0; j < 4; ++j) {
                        float e = exp2f(fmaf(acc[m][n][j], C10, -C10));
                        rs[m][j] += e;
                        cs[n] += e;
                    }
            #pragma unroll
            for (int n = 0; n < 4; ++n) {
                float v = cs[n];
                v += __shfl_xor(v, 16);
                v += __shfl_xor(v, 32);
                if (lg == 0)
                    atomicAdd(&colsum[p * NB + bxg * 128 + wc * 64 + n * 16 + lr], v);
            }
            #pragma unroll
            for (int m = 0; m < 4; ++m)
                #pragma unroll
                for (int n = 0; n < 4; ++n)
                    acc[m][n] = (f32x4){0.f, 0.f, 0.f, 0.f};
        }

        if (s < 15) {
            asm volatile("s_waitcnt vmcnt(0)" ::: "memory");
            __builtin_amdgcn_s_barrier();
        }
    }
    #undef STAGE
    #undef LDF

    // ---- final rowsum flush (accumulated over all 4 bx tiles) ----
    #pragma unroll
    for (int m = 0; m < 4; ++m)
        #pragma unroll
        for (int j = 0; j < 4; ++j) {
            float v = rs[m][j];
            v += __shfl_xor(v, 1);
            v += __shfl_xor(v, 2);
            v += __shfl_xor(v, 4);
            v += __shfl_xor(v, 8);
            if (lr == 0)
                atomicAdd(&rowsum[p * NB + by * 128 + wr * 64 + m * 16 + lg * 4 + j], v);
        }
}

// ---------------- final reduce ----------------
__global__ __launch_bounds__(1024) void finalize_kernel(
    const float* __restrict__ rowsum, const float* __restrict__ colsum,
    const float* __restrict__ diag, float* __restrict__ out)
{
    float s = 0.f;
    for (int i = threadIdx.x; i < 3 * NB; i += 1024) {
        s += 0.5f * (logf(rowsum[i]) + logf(colsum[i])) + 10.0f - 10.0f * diag[i];
    }
    #pragma unroll
    for (int m = 32; m >= 1; m >>= 1) s += __shfl_xor(s, m);
    __shared__ float sw[16];
    if ((threadIdx.x & 63) == 0) sw[threadIdx.x >> 6] = s;
    __syncthreads();
    if (threadIdx.x == 0) {
        float t = 0.f;
        #pragma unroll
        for (int i = 0; i < 16; ++i) t += sw[i];
        out[0] = t * (1.0f / (3.0f * NB));
    }
}

extern "C" void kernel_launch(void* const* d_in, const int* in_sizes, int n_in,
                              void* d_out, int out_size, void* d_ws, size_t ws_size,
                              hipStream_t stream) {
    const float* z0 = (const float*)d_in[0];
    const float* z1 = (const float*)d_in[1];
    const float* z2 = (const float*)d_in[2];
    float* out = (float*)d_out;

    char* ws = (char*)d_ws;
    unsigned char* nrm8 = (unsigned char*)ws;               // 3*4096*512 fp8 = 6.3 MB
    const size_t nrm_bytes = (size_t)3 * NB * ND;
    float* rowsum = (float*)(ws + nrm_bytes);               // 3*4096 f32
    float* colsum = rowsum + 3 * NB;                        // 3*4096 f32
    float* diag = colsum + 3 * NB;                          // 3*4096 f32 (fully overwritten)

    nrm_kernel<<<dim3(NB / 4, 3), 256, 0, stream>>>(z0, z1, z2, nrm8, rowsum, colsum);
    pair_gemm_kernel<<<768, 256, 0, stream>>>(nrm8, rowsum, colsum, diag);
    finalize_kernel<<<1, 1024, 0, stream>>>(rowsum, colsum, diag, out);
}